// Round 4
// baseline (157.824 us; speedup 1.0000x reference)
//
#include <hip/hip_runtime.h>

// NCC2D fused: 5 box-sums (9x9, zero-pad) + cc + global mean, single pass.
// Thread owns 2 columns; horizontal 9-sums from global halo loads (L1-absorbed
// overlap); vertical 9-row running window in a register ring.
// R4 change: ring[9][5]/vI[10]/vJ[10] arrays -> 45+20 NAMED float2 scalars via
// macros. R1/R3 counters proved the arrays live in scratch (VGPR=72 frozen,
// WRITE_SIZE 53MB of spill traffic vs 6.6KB real output; launch_bounds no-op)
// -- rule #20: allocas indexed by loop vars never get promoted. Named scalars
// force register allocation.
// d_ws: 1664 block partials (float). Kernel 2 reduces in double -> -mean.

#define BATCH   32
#define IMH     512
#define IMW     512
#define SH      10          // output rows per block
#define NSTRIP  52          // ceil(512/10); 52*10 = 520 (tail masked)
#define NPART   (BATCH * NSTRIP)

// load one even-aligned float2 pair from both images, zero outside [0,IMW)
#define LOADP(CK, IVv, JVv) do {                                           \
    const int ck_ = (CK);                                                  \
    if ((unsigned)ck_ < (unsigned)IMW) {                                   \
        IVv = *(const float2*)(rowI + ck_);                                \
        JVv = *(const float2*)(rowJ + ck_);                                \
    } else {                                                               \
        IVv = make_float2(0.f, 0.f); JVv = make_float2(0.f, 0.f);          \
    }                                                                      \
} while (0)

// one input row: load 10 cols, horizontal 9-window sums for 2 owned columns,
// vertical ring update against slot (S0..S4), emit when IT >= 8.
#define NCC_STEP(IT, S0, S1, S2, S3, S4) do {                              \
    const int it_ = (IT);                                                  \
    const int ri_ = r0 - 4 + it_;                                          \
    float2 iv0, iv1, iv2, iv3, iv4, jv0, jv1, jv2, jv3, jv4;               \
    if ((unsigned)ri_ < (unsigned)IMH) {                                   \
        const float* rowI = Ib + (size_t)ri_ * IMW;                        \
        const float* rowJ = Jb + (size_t)ri_ * IMW;                        \
        LOADP(cbase,     iv0, jv0);                                        \
        LOADP(cbase + 2, iv1, jv1);                                        \
        LOADP(cbase + 4, iv2, jv2);                                        \
        LOADP(cbase + 6, iv3, jv3);                                        \
        LOADP(cbase + 8, iv4, jv4);                                        \
    } else {                                                               \
        iv0 = iv1 = iv2 = iv3 = iv4 = make_float2(0.f, 0.f);               \
        jv0 = jv1 = jv2 = jv3 = jv4 = make_float2(0.f, 0.f);               \
    }                                                                      \
    const float sI  = ((iv0.x + iv0.y) + (iv1.x + iv1.y))                  \
                    + ((iv2.x + iv2.y) + (iv3.x + iv3.y)) + iv4.x;         \
    const float sJ  = ((jv0.x + jv0.y) + (jv1.x + jv1.y))                  \
                    + ((jv2.x + jv2.y) + (jv3.x + jv3.y)) + jv4.x;         \
    const float sII = ((iv0.x*iv0.x + iv0.y*iv0.y) + (iv1.x*iv1.x + iv1.y*iv1.y)) \
                    + ((iv2.x*iv2.x + iv2.y*iv2.y) + (iv3.x*iv3.x + iv3.y*iv3.y)) \
                    + iv4.x*iv4.x;                                         \
    const float sJJ = ((jv0.x*jv0.x + jv0.y*jv0.y) + (jv1.x*jv1.x + jv1.y*jv1.y)) \
                    + ((jv2.x*jv2.x + jv2.y*jv2.y) + (jv3.x*jv3.x + jv3.y*jv3.y)) \
                    + jv4.x*jv4.x;                                         \
    const float sIJ = ((iv0.x*jv0.x + iv0.y*jv0.y) + (iv1.x*jv1.x + iv1.y*jv1.y)) \
                    + ((iv2.x*jv2.x + iv2.y*jv2.y) + (iv3.x*jv3.x + iv3.y*jv3.y)) \
                    + iv4.x*jv4.x;                                         \
    float2 Hn0, Hn1, Hn2, Hn3, Hn4;                                        \
    Hn0.x = sI;  Hn0.y = sI  + iv4.y         - iv0.x;                      \
    Hn1.x = sJ;  Hn1.y = sJ  + jv4.y         - jv0.x;                      \
    Hn2.x = sII; Hn2.y = sII + iv4.y*iv4.y   - iv0.x*iv0.x;                \
    Hn3.x = sJJ; Hn3.y = sJJ + jv4.y*jv4.y   - jv0.x*jv0.x;                \
    Hn4.x = sIJ; Hn4.y = sIJ + iv4.y*jv4.y   - iv0.x*jv0.x;                \
    V0.x += Hn0.x - S0.x; V0.y += Hn0.y - S0.y; S0 = Hn0;                  \
    V1.x += Hn1.x - S1.x; V1.y += Hn1.y - S1.y; S1 = Hn1;                  \
    V2.x += Hn2.x - S2.x; V2.y += Hn2.y - S2.y; S2 = Hn2;                  \
    V3.x += Hn3.x - S3.x; V3.y += Hn3.y - S3.y; S3 = Hn3;                  \
    V4.x += Hn4.x - S4.x; V4.y += Hn4.y - S4.y; S4 = Hn4;                  \
    if (it_ >= 8) {                                                        \
        const int r_ = r0 + it_ - 8;                                       \
        if (r_ < IMH) {                                                    \
            {                                                              \
                const float aI = V0.x, aJ = V1.x;                          \
                const float cross = V4.x - aI * aJ * inv81;                \
                const float iva   = V2.x - aI * aI * inv81;                \
                const float jva   = V3.x - aJ * aJ * inv81;                \
                acc.x += cross * cross *                                   \
                         __builtin_amdgcn_rcpf(iva * jva + 1e-5f);         \
            }                                                              \
            {                                                              \
                const float aI = V0.y, aJ = V1.y;                          \
                const float cross = V4.y - aI * aJ * inv81;                \
                const float iva   = V2.y - aI * aI * inv81;                \
                const float jva   = V3.y - aJ * aJ * inv81;                \
                acc.y += cross * cross *                                   \
                         __builtin_amdgcn_rcpf(iva * jva + 1e-5f);         \
            }                                                              \
        }                                                                  \
    }                                                                      \
} while (0)

#define DECL_SLOT(P) float2 P##0 = z_, P##1 = z_, P##2 = z_, P##3 = z_, P##4 = z_

__global__ __launch_bounds__(256, 2) void ncc_main(const float* __restrict__ I,
                                                   const float* __restrict__ J,
                                                   float* __restrict__ partial) {
    const int t  = threadIdx.x;
    const int s  = blockIdx.x;   // strip
    const int b  = blockIdx.y;   // image
    const int r0 = s * SH;       // first output row of strip
    const float inv81 = 1.0f / 81.0f;

    const float* Ib = I + (size_t)b * IMH * IMW;
    const float* Jb = J + (size_t)b * IMH * IMW;

    const int cbase = 2 * t - 4; // leftmost halo column for this thread

    const float2 z_ = make_float2(0.f, 0.f);
    // 9 ring slots x 5 quantities (I, J, II, JJ, IJ), all named scalars
    DECL_SLOT(rA); DECL_SLOT(rB); DECL_SLOT(rC); DECL_SLOT(rD); DECL_SLOT(rE);
    DECL_SLOT(rF); DECL_SLOT(rG); DECL_SLOT(rH); DECL_SLOT(rI);
    float2 V0 = z_, V1 = z_, V2 = z_, V3 = z_, V4 = z_;
    float2 acc = z_;

#pragma unroll 1
    for (int g = 0; g < 2; ++g) {        // 18 input rows = 2 * 9
        const int base = g * 9;
        NCC_STEP(base + 0, rA0, rA1, rA2, rA3, rA4);
        NCC_STEP(base + 1, rB0, rB1, rB2, rB3, rB4);
        NCC_STEP(base + 2, rC0, rC1, rC2, rC3, rC4);
        NCC_STEP(base + 3, rD0, rD1, rD2, rD3, rD4);
        NCC_STEP(base + 4, rE0, rE1, rE2, rE3, rE4);
        NCC_STEP(base + 5, rF0, rF1, rF2, rF3, rF4);
        NCC_STEP(base + 6, rG0, rG1, rG2, rG3, rG4);
        NCC_STEP(base + 7, rH0, rH1, rH2, rH3, rH4);
        NCC_STEP(base + 8, rI0, rI1, rI2, rI3, rI4);
    }

    // block reduction: wave shuffle, then LDS across the 4 waves
    float sum = acc.x + acc.y;
#pragma unroll
    for (int off = 32; off > 0; off >>= 1) sum += __shfl_down(sum, off, 64);

    __shared__ float wsum[4];
    if ((t & 63) == 0) wsum[t >> 6] = sum;
    __syncthreads();
    if (t == 0) {
        partial[(size_t)b * NSTRIP + s] = wsum[0] + wsum[1] + wsum[2] + wsum[3];
    }
}

__global__ __launch_bounds__(256) void ncc_reduce(const float* __restrict__ partial,
                                                  float* __restrict__ out) {
    const int t = threadIdx.x;
    double ssum = 0.0;
    for (int idx = t; idx < NPART; idx += 256) ssum += (double)partial[idx];
#pragma unroll
    for (int off = 32; off > 0; off >>= 1) ssum += __shfl_down(ssum, off, 64);

    __shared__ double wsum[4];
    if ((t & 63) == 0) wsum[t >> 6] = ssum;
    __syncthreads();
    if (t == 0) {
        const double total = wsum[0] + wsum[1] + wsum[2] + wsum[3];
        out[0] = (float)(-total / 8388608.0);  // -mean over 32*512*512
    }
}

extern "C" void kernel_launch(void* const* d_in, const int* in_sizes, int n_in,
                              void* d_out, int out_size, void* d_ws, size_t ws_size,
                              hipStream_t stream) {
    const float* I = (const float*)d_in[0];  // y_true
    const float* J = (const float*)d_in[1];  // y_pred
    float* partial = (float*)d_ws;           // NPART floats
    float* out     = (float*)d_out;

    dim3 grid(NSTRIP, BATCH);
    ncc_main<<<grid, 256, 0, stream>>>(I, J, partial);
    ncc_reduce<<<1, 256, 0, stream>>>(partial, out);
}